// Round 9
// baseline (14.391 us; speedup 1.0000x reference)
//
#include <hip/hip_runtime.h>

typedef __attribute__((ext_vector_type(8))) short bf16x8;
typedef __attribute__((ext_vector_type(4))) float f32x4;

#define NEXP 16
#define FIN 256
#define FOUT 256
#define NB 16
#define MAT4 (FIN * FOUT / 4)   // float4 per (IN,OUT) expert matrix

// fp32 -> bf16 round-to-nearest-even (finite inputs)
__device__ __forceinline__ unsigned short f2bf(float f) {
    unsigned int u = __float_as_uint(f);
    return (unsigned short)((u + 0x7fffu + ((u >> 16) & 1u)) >> 16);
}

// ---------------------------------------------------------------------------
// Single fused kernel. 256 blocks x 1024 threads (16 waves, 1 block/CU).
// Block = (graph g, 16-col slice cs):
//   - each thread gathers its MFMA B-fragment rows DIRECTLY from global fp32
//     (8x dwordx4, issued first; overlaps the mix) -- no x-tile LDS at all
//   - mix the 256x16 kernel slice in fp32 (16 loads/thread), write bf16
//     transposed tile msT[n=16][k=256] (XOR-swizzled 16B granules) to LDS
//   - barrier -> 4x mfma_f32_16x16x32_bf16 per wave
//     (8 row-tiles x 2-way K-split over 16 waves)
//   - K-pair reduce via 8 KB LDS + bias + float4 store.
// LDS: 8 KB msT + 8 KB reduce = 16 KB.
// XCD swizzle: the 2 slices sharing each kern 128B line sit on one XCD.
// ---------------------------------------------------------------------------
__global__ __launch_bounds__(1024, 4) void mole_onepass_kernel(
    const float* __restrict__ inp,     // (N, IN)
    const int* __restrict__ n_node,    // (B,)
    const float* __restrict__ coeffs,  // (B, E)
    const float* __restrict__ kern,    // (E, IN, OUT)
    const float* __restrict__ bias,    // (OUT,)
    float* __restrict__ out)           // (N, OUT)
{
    __shared__ char ms_base[8192];          // msT bf16 [16][512B], swizzled
    __shared__ f32x4 red[512];              // [tile 8][lane 64]

    const int tid = threadIdx.x;
    const int bid = blockIdx.x;
    const int lane = tid & 63;
    const int wv = tid >> 6;

    // XCD-chunked decode: xcd = bid&7 owns column slices {2*xcd, 2*xcd+1}
    const int xcd = bid & 7;
    const int j0 = bid >> 3;                // 0..31
    const int cslice = 2 * xcd + (j0 & 1);  // column slice 0..15
    const int g = j0 >> 1;                  // graph 0..15
    const int co4 = cslice * 4;             // float4 column offset

    // graph row range via prefix scan (ragged-safe, block-uniform scalar)
    int start = 0;
#pragma unroll
    for (int b = 0; b < NB; ++b) {
        const int nb = n_node[b];
        start += (b < g) ? nb : 0;
    }
    const int cnt = n_node[g];

    const float4* k4 = reinterpret_cast<const float4*>(kern);
    const float4* ip4 = reinterpret_cast<const float4*>(inp);
    float4* out4 = reinterpret_cast<float4*>(out);
    const float4* bias4 = reinterpret_cast<const float4*>(bias);

    // MFMA decomposition (wave-uniform): row-tile tr, K-half kh
    const int tr = wv & 7;
    const int kh = wv >> 3;
    const int ln = lane & 15;
    const int lg = lane >> 4;               // 0..3
    const int xr = tr * 16 + ln;            // local x-row this lane feeds (B)

    for (int r0 = 0; r0 < cnt; r0 += 128) {
        const int rows = min(128, cnt - r0);

        // ---- gather B-fragment rows directly from global (fp32) ----------
        // lane covers row xr, k-range [kc*32 + lg*8, +8) for kc = kh*4+kc8
        float4 f0[4], f1[4];
        {
            const float4* xrow = ip4 + (size_t)(start + r0 + xr) * 64;
            const bool v = (xr < rows);
#pragma unroll
            for (int kc8 = 0; kc8 < 4; ++kc8) {
                const int kc = kh * 4 + kc8;
                const int fi = kc * 8 + lg * 2;
                f0[kc8] = v ? xrow[fi] : make_float4(0.f, 0.f, 0.f, 0.f);
                f1[kc8] = v ? xrow[fi + 1] : make_float4(0.f, 0.f, 0.f, 0.f);
            }
        }

        // ---- mix (first chunk only; fp32 exact), write bf16 msT ----------
        if (r0 == 0) {
            const int mi = tid >> 2;        // k index 0..255
            const int mc4 = tid & 3;        // f4-col within 16-wide slice
            const float4* kp = k4 + (size_t)mi * (FOUT / 4) + co4 + mc4;
            float4 macc = make_float4(0.f, 0.f, 0.f, 0.f);
#pragma unroll
            for (int e = 0; e < NEXP; ++e) {
                const float4 kv = kp[(size_t)e * MAT4];
                const float c = coeffs[g * NEXP + e];
                macc.x += c * kv.x;
                macc.y += c * kv.y;
                macc.z += c * kv.z;
                macc.w += c * kv.w;
            }
            // msT[n][k=mi], byte = n*512 + swizzled granule(mi>>3) + (mi&7)*2
            const float mv[4] = {macc.x, macc.y, macc.z, macc.w};
#pragma unroll
            for (int s = 0; s < 4; ++s) {
                const int n = mc4 * 4 + s;
                const int byte = n * 512 + ((((mi >> 3) ^ (n & 7)) << 4))
                               + (mi & 7) * 2;
                *reinterpret_cast<unsigned short*>(ms_base + byte) = f2bf(mv[s]);
            }
        }
        __syncthreads();   // r0==0: msT visible; r0>0: red reuse ordering

        // ---- MFMA GEMM: D[n][r] = sum_k msT[n][k] * x[r][k] ---------------
        f32x4 acc = {0.f, 0.f, 0.f, 0.f};
#pragma unroll
        for (int kc8 = 0; kc8 < 4; ++kc8) {
            const int kc = kh * 4 + kc8;    // K-chunk of 32
            const int gran = kc * 4 + lg;   // 16B granule index along k
            const bf16x8 a = *reinterpret_cast<const bf16x8*>(
                ms_base + ln * 512 + ((gran ^ (ln & 7)) << 4));
            bf16x8 b;
            b[0] = (short)f2bf(f0[kc8].x);
            b[1] = (short)f2bf(f0[kc8].y);
            b[2] = (short)f2bf(f0[kc8].z);
            b[3] = (short)f2bf(f0[kc8].w);
            b[4] = (short)f2bf(f1[kc8].x);
            b[5] = (short)f2bf(f1[kc8].y);
            b[6] = (short)f2bf(f1[kc8].z);
            b[7] = (short)f2bf(f1[kc8].w);
            acc = __builtin_amdgcn_mfma_f32_16x16x32_bf16(a, b, acc, 0, 0, 0);
        }

        if (kh == 1) red[tr * 64 + lane] = acc;
        __syncthreads();

        if (kh == 0) {
            const f32x4 p = red[tr * 64 + lane];
            const int r = tr * 16 + ln;     // local output row (= D col)
            if (r < rows) {
                const float4 bv = bias4[co4 + lg];
                float4 o;
                o.x = acc[0] + p[0] + bv.x;
                o.y = acc[1] + p[1] + bv.y;
                o.z = acc[2] + p[2] + bv.z;
                o.w = acc[3] + p[3] + bv.w;
                out4[(size_t)(start + r0 + r) * 64 + co4 + lg] = o;
            }
        }
    }
}

// ---------------------------------------------------------------------------
extern "C" void kernel_launch(void* const* d_in, const int* in_sizes, int n_in,
                              void* d_out, int out_size, void* d_ws, size_t ws_size,
                              hipStream_t stream) {
    const float* inputs = (const float*)d_in[0];   // (N, IN) f32
    const int* n_node = (const int*)d_in[1];       // (B,) i32
    const float* coeffs = (const float*)d_in[2];   // (B, E) f32
    const float* kern = (const float*)d_in[3];     // (E, IN, OUT) f32
    const float* bias = (const float*)d_in[4];     // (OUT,) f32
    float* outp = (float*)d_out;                   // (N, OUT) f32

    mole_onepass_kernel<<<256, 1024, 0, stream>>>(
        inputs, n_node, coeffs, kern, bias, outp);
}

// Round 10
// 12.710 us; speedup vs baseline: 1.1322x; 1.1322x over previous
//
#include <hip/hip_runtime.h>

typedef __attribute__((ext_vector_type(8))) short bf16x8;
typedef __attribute__((ext_vector_type(4))) float f32x4;

#define NEXP 16
#define FIN 256
#define FOUT 256
#define NB 16
#define MAT4 (FIN * FOUT / 4)   // float4 per (IN,OUT) expert matrix

// fp32 -> bf16 round-to-nearest-even (finite inputs)
__device__ __forceinline__ unsigned short f2bf(float f) {
    unsigned int u = __float_as_uint(f);
    return (unsigned short)((u + 0x7fffu + ((u >> 16) & 1u)) >> 16);
}

// ---------------------------------------------------------------------------
// Single fused kernel (r8 structure — best measured at 12.64 us).
// 256 blocks x 1024 threads (16 waves, 1 block/CU).
// Block = (graph g, 16-col slice cs):
//   - issue 8 input-row staging loads (fp32, registers, fully coalesced)
//   - mix the 256x16 kernel slice in fp32 (16 loads/thread), write bf16
//     TRANSPOSED tile msT[n=16][k=256] (XOR-swizzled 16B granules)
//   - drain staged rows as bf16 x-tile xs[r=128][k=256] (same swizzle)
//   - barrier -> MFMA GEMM: 8 row-tiles x 2-way K-split over 16 waves,
//     4x mfma_f32_16x16x32_bf16 each; one ds_read_b128 per operand per mfma
//   - K-pair reduce via 8 KB LDS + bias + float4 store.
// LDS: 64 KB x-tile + 8 KB msT + 8 KB reduce = 80 KB.
// XCD swizzle: the 2 slices sharing each kern 128B line sit on one XCD.
// ---------------------------------------------------------------------------
__global__ __launch_bounds__(1024, 4) void mole_onepass_kernel(
    const float* __restrict__ inp,     // (N, IN)
    const int* __restrict__ n_node,    // (B,)
    const float* __restrict__ coeffs,  // (B, E)
    const float* __restrict__ kern,    // (E, IN, OUT)
    const float* __restrict__ bias,    // (OUT,)
    float* __restrict__ out)           // (N, OUT)
{
    __shared__ float4 smem4[5120];          // 81920 B
    char* const smem = (char*)smem4;
    char* const xs_base = smem;             // x-tile bf16 [128][512B]
    char* const ms_base = smem + 65536;     // msT  bf16 [16][512B]
    f32x4* const red = (f32x4*)(smem + 73728);  // [8][64] f32x4

    const int tid = threadIdx.x;
    const int bid = blockIdx.x;
    const int lane = tid & 63;
    const int wv = tid >> 6;

    // XCD-chunked decode: xcd = bid&7 owns column slices {2*xcd, 2*xcd+1}
    const int xcd = bid & 7;
    const int j0 = bid >> 3;                // 0..31
    const int cslice = 2 * xcd + (j0 & 1);  // column slice 0..15
    const int g = j0 >> 1;                  // graph 0..15
    const int co4 = cslice * 4;             // float4 column offset

    // graph row range via prefix scan (ragged-safe, block-uniform scalar)
    int start = 0;
#pragma unroll
    for (int b = 0; b < NB; ++b) {
        const int nb = n_node[b];
        start += (b < g) ? nb : 0;
    }
    const int cnt = n_node[g];

    const float4* k4 = reinterpret_cast<const float4*>(kern);
    const float4* ip4 = reinterpret_cast<const float4*>(inp);
    float4* out4 = reinterpret_cast<float4*>(out);
    const float4* bias4 = reinterpret_cast<const float4*>(bias);

    // MFMA decomposition (wave-uniform): row-tile tr, K-half kh
    const int tr = wv & 7;
    const int kh = wv >> 3;
    const int ln = lane & 15;
    const int lg = lane >> 4;               // 0..3

    for (int r0 = 0; r0 < cnt; r0 += 128) {
        const int rows = min(128, cnt - r0);

        // ---- issue input staging loads (guarded; zeros for missing rows) --
        float4 st[8];
        const float4* ib = ip4 + (size_t)(start + r0) * 64;
#pragma unroll
        for (int k = 0; k < 8; ++k) {
            const int row = (tid >> 6) + 16 * k;
            st[k] = (row < rows) ? ib[tid + 1024 * k]
                                 : make_float4(0.f, 0.f, 0.f, 0.f);
        }

        // ---- mix (first chunk only; fp32 exact), write bf16 msT ----------
        if (r0 == 0) {
            const int mi = tid >> 2;        // k index 0..255
            const int mc4 = tid & 3;        // f4-col within 16-wide slice
            const float4* kp = k4 + (size_t)mi * (FOUT / 4) + co4 + mc4;
            float4 macc = make_float4(0.f, 0.f, 0.f, 0.f);
#pragma unroll
            for (int e = 0; e < NEXP; ++e) {
                const float4 kv = kp[(size_t)e * MAT4];
                const float c = coeffs[g * NEXP + e];
                macc.x += c * kv.x;
                macc.y += c * kv.y;
                macc.z += c * kv.z;
                macc.w += c * kv.w;
            }
            // msT[n][k=mi], byte = n*512 + swz granule(mi>>3) + (mi&7)*2
            const float mv[4] = {macc.x, macc.y, macc.z, macc.w};
#pragma unroll
            for (int s = 0; s < 4; ++s) {
                const int n = mc4 * 4 + s;
                const int byte = n * 512 + ((((mi >> 3) ^ (n & 7)) << 4))
                               + (mi & 7) * 2;
                *reinterpret_cast<unsigned short*>(ms_base + byte) = f2bf(mv[s]);
            }
        }

        // ---- drain staged rows as bf16 x-tile (swizzled) ------------------
#pragma unroll
        for (int k = 0; k < 8; ++k) {
            const int row = (tid >> 6) + 16 * k;
            const int c4 = tid & 63;        // f4 index -> k = c4*4..+3
            ushort4 p;
            p.x = f2bf(st[k].x);
            p.y = f2bf(st[k].y);
            p.z = f2bf(st[k].z);
            p.w = f2bf(st[k].w);
            const int byte = row * 512 + ((((c4 >> 1) ^ (row & 7)) << 4))
                           + (c4 & 1) * 8;
            *reinterpret_cast<ushort4*>(xs_base + byte) = p;
        }
        __syncthreads();

        // ---- MFMA GEMM: D[n][r] = sum_k msT[n][k] * x[r][k] ---------------
        f32x4 acc = {0.f, 0.f, 0.f, 0.f};
        const int xr = tr * 16 + ln;        // local x-row for B-frag
#pragma unroll
        for (int kc8 = 0; kc8 < 4; ++kc8) {
            const int kc = kh * 4 + kc8;    // K-chunk of 32
            const int gran = kc * 4 + lg;   // 16B granule index along k
            const bf16x8 a = *reinterpret_cast<const bf16x8*>(
                ms_base + ln * 512 + ((gran ^ (ln & 7)) << 4));
            const bf16x8 b = *reinterpret_cast<const bf16x8*>(
                xs_base + xr * 512 + ((gran ^ (xr & 7)) << 4));
            acc = __builtin_amdgcn_mfma_f32_16x16x32_bf16(a, b, acc, 0, 0, 0);
        }

        if (kh == 1) red[tr * 64 + lane] = acc;
        __syncthreads();

        if (kh == 0) {
            const f32x4 p = red[tr * 64 + lane];
            const int r = tr * 16 + ln;     // local output row (= D col)
            if (r < rows) {
                const float4 bv = bias4[co4 + lg];
                float4 o;
                o.x = acc[0] + p[0] + bv.x;
                o.y = acc[1] + p[1] + bv.y;
                o.z = acc[2] + p[2] + bv.z;
                o.w = acc[3] + p[3] + bv.w;
                out4[(size_t)(start + r0 + r) * 64 + co4 + lg] = o;
            }
        }
        // next chunk's staging (global loads) + drain happen after the
        // reduce barrier; x-tile readers (MFMA) all completed before it.
    }
}

// ---------------------------------------------------------------------------
extern "C" void kernel_launch(void* const* d_in, const int* in_sizes, int n_in,
                              void* d_out, int out_size, void* d_ws, size_t ws_size,
                              hipStream_t stream) {
    const float* inputs = (const float*)d_in[0];   // (N, IN) f32
    const int* n_node = (const int*)d_in[1];       // (B,) i32
    const float* coeffs = (const float*)d_in[2];   // (B, E) f32
    const float* kern = (const float*)d_in[3];     // (E, IN, OUT) f32
    const float* bias = (const float*)d_in[4];     // (OUT,) f32
    float* outp = (float*)d_out;                   // (N, OUT) f32

    mole_onepass_kernel<<<256, 1024, 0, stream>>>(
        inputs, n_node, coeffs, kern, bias, outp);
}